// Round 4
// baseline (1455.533 us; speedup 1.0000x reference)
//
#include <hip/hip_runtime.h>

#define LNEPS 1e-5f
#define AEPS 1e-8f
#define SCALE_Q 0.036084391824351615f  // 768^-0.5

// ---------------- LN stats over input rows (mean, rstd) ----------------
__global__ void ln_stats_k(const float* __restrict__ in, float* __restrict__ mean,
                           float* __restrict__ rstd) {
  int row = blockIdx.x, t = threadIdx.x;
  const float* p = in + (size_t)row * 768;
  float v0 = p[t], v1 = p[t + 256], v2 = p[t + 512];
  float s = v0 + v1 + v2, ss = v0 * v0 + v1 * v1 + v2 * v2;
#pragma unroll
  for (int o = 32; o; o >>= 1) { s += __shfl_down(s, o); ss += __shfl_down(ss, o); }
  __shared__ float sa[4], sb[4];
  if ((t & 63) == 0) { sa[t >> 6] = s; sb[t >> 6] = ss; }
  __syncthreads();
  if (t == 0) {
    float S = sa[0] + sa[1] + sa[2] + sa[3], SS = sb[0] + sb[1] + sb[2] + sb[3];
    float m = S * (1.f / 768.f);
    float var = SS * (1.f / 768.f) - m * m;
    mean[row] = m;
    rstd[row] = rsqrtf(var + LNEPS);
  }
}

// ---------------- transpose 768x768 fp32: WT[c][i] = W[i][c] ----------------
__global__ void packT_k(const float* __restrict__ W, float* __restrict__ WT) {
  __shared__ float tile[32][33];
  int c0 = blockIdx.x * 32, i0 = blockIdx.y * 32;
  int tx = threadIdx.x & 31, ty = threadIdx.x >> 5;  // 32x8
#pragma unroll
  for (int k = 0; k < 4; ++k)
    tile[ty + 8 * k][tx] = W[(size_t)(i0 + ty + 8 * k) * 768 + c0 + tx];
  __syncthreads();
#pragma unroll
  for (int k = 0; k < 4; ++k)
    WT[(size_t)(c0 + ty + 8 * k) * 768 + i0 + tx] = tile[tx][ty + 8 * k];
}

// ---------------- broadcast slots to all batch rows ----------------
__global__ void init_slots_k(const float* __restrict__ s0, float* __restrict__ slots) {
  int idx = blockIdx.x * 256 + threadIdx.x;  // 196608
  slots[idx] = s0[idx % 6144];
}

// ---------------- q_prep: LN(slots) -> q -> qk = q@Wk^T, qbk = q.bk ----------------
__global__ void q_prep_k(const float* __restrict__ slots, const float* __restrict__ g_s,
                         const float* __restrict__ b_s, const float* __restrict__ Wq,
                         const float* __restrict__ bq, const float* __restrict__ WkT,
                         const float* __restrict__ bk, float* __restrict__ qk,
                         float* __restrict__ qbk) {
  __shared__ float sn[4][768];
  __shared__ float qq[4][768];
  int r0 = blockIdx.x * 4, t = threadIdx.x, w = t >> 6, l = t & 63;
  const float* sr = slots + (size_t)(r0 + w) * 768;
  float v[12], s = 0.f, ss = 0.f;
#pragma unroll
  for (int j = 0; j < 12; ++j) { v[j] = sr[l + 64 * j]; s += v[j]; ss += v[j] * v[j]; }
#pragma unroll
  for (int o = 32; o; o >>= 1) { s += __shfl_xor(s, o); ss += __shfl_xor(ss, o); }
  float m = s * (1.f / 768.f), rs = rsqrtf(ss * (1.f / 768.f) - m * m + LNEPS);
#pragma unroll
  for (int j = 0; j < 12; ++j) {
    int i = l + 64 * j;
    sn[w][i] = (v[j] - m) * rs * g_s[i] + b_s[i];
  }
  __syncthreads();
  {  // q = sn @ Wq + bq
    float acc[4][3];
#pragma unroll
    for (int r = 0; r < 4; ++r)
#pragma unroll
      for (int c = 0; c < 3; ++c) acc[r][c] = bq[t + 256 * c];
    for (int i = 0; i < 768; ++i) {
      float w0 = Wq[(size_t)i * 768 + t];
      float w1 = Wq[(size_t)i * 768 + t + 256];
      float w2 = Wq[(size_t)i * 768 + t + 512];
#pragma unroll
      for (int r = 0; r < 4; ++r) {
        float a = sn[r][i];
        acc[r][0] += a * w0; acc[r][1] += a * w1; acc[r][2] += a * w2;
      }
    }
#pragma unroll
    for (int r = 0; r < 4; ++r)
#pragma unroll
      for (int c = 0; c < 3; ++c) qq[r][t + 256 * c] = acc[r][c];
  }
  __syncthreads();
  {  // qbk[row] = q . bk  (per-wave reduce)
    float qb = 0.f;
#pragma unroll
    for (int j = 0; j < 12; ++j) { int i = l + 64 * j; qb += qq[w][i] * bk[i]; }
#pragma unroll
    for (int o = 32; o; o >>= 1) qb += __shfl_xor(qb, o);
    if (l == 0) qbk[r0 + w] = qb;
  }
  {  // qk = q @ WkT^T rows: qk[row][i2] = sum_d q[row][d]*WkT[d][i2]
    float acc[4][3] = {};
    for (int d = 0; d < 768; ++d) {
      float w0 = WkT[(size_t)d * 768 + t];
      float w1 = WkT[(size_t)d * 768 + t + 256];
      float w2 = WkT[(size_t)d * 768 + t + 512];
#pragma unroll
      for (int r = 0; r < 4; ++r) {
        float a = qq[r][d];
        acc[r][0] += a * w0; acc[r][1] += a * w1; acc[r][2] += a * w2;
      }
    }
#pragma unroll
    for (int r = 0; r < 4; ++r)
#pragma unroll
      for (int c = 0; c < 3; ++c) qk[(size_t)(r0 + r) * 768 + t + 256 * c] = acc[r][c];
  }
}

// ---------------- fused dots+softmax+pool, one pass over inputs ----------------
// grid (16 chunks, 32 b), 256 thr. Writes attnbuf[b][n][8], partials[chunk][bs][768], asump
__global__ void attn_pool_k(const float* __restrict__ in, const float* __restrict__ mean,
                            const float* __restrict__ rstd, const float* __restrict__ g_in,
                            const float* __restrict__ b_in, const float* __restrict__ qk,
                            const float* __restrict__ qbk, float* __restrict__ attnbuf,
                            float* __restrict__ partials, float* __restrict__ asump) {
  __shared__ float qks[8][768];
  __shared__ float pooled[8][768];
  __shared__ float xs[4][768];
  __shared__ float at4[4][8];
  __shared__ float asums[8];
  __shared__ float qbks[8];
  int chunk = blockIdx.x, b = blockIdx.y, t = threadIdx.x, w = t >> 6, l = t & 63;
  for (int i = t; i < 6144; i += 256) {
    ((float*)qks)[i] = qk[(size_t)b * 6144 + i];
    ((float*)pooled)[i] = 0.f;
  }
  if (t < 8) { asums[t] = 0.f; qbks[t] = qbk[b * 8 + t]; }
  __syncthreads();
  for (int rnd = 0; rnd < 16; ++rnd) {
    int n = chunk * 64 + rnd * 4 + w;
    int row = b * 1024 + n;
    const float* xp = in + (size_t)row * 768;
    float mu = mean[row], rs = rstd[row];
    float dots[8] = {};
#pragma unroll
    for (int j = 0; j < 12; ++j) {
      int d = l + 64 * j;
      float xv = (xp[d] - mu) * rs * g_in[d] + b_in[d];
      xs[w][d] = xv;
#pragma unroll
      for (int s2 = 0; s2 < 8; ++s2) dots[s2] += qks[s2][d] * xv;
    }
#pragma unroll
    for (int s2 = 0; s2 < 8; ++s2)
#pragma unroll
      for (int o = 32; o; o >>= 1) dots[s2] += __shfl_xor(dots[s2], o);
    float sc[8];
#pragma unroll
    for (int s2 = 0; s2 < 8; ++s2) sc[s2] = (dots[s2] + qbks[s2]) * SCALE_Q;
    float mx = sc[0];
#pragma unroll
    for (int s2 = 1; s2 < 8; ++s2) mx = fmaxf(mx, sc[s2]);
    float e[8], se = 0.f;
#pragma unroll
    for (int s2 = 0; s2 < 8; ++s2) { e[s2] = expf(sc[s2] - mx); se += e[s2]; }
    float inv_se = 1.f / se;
    float av = e[0] * inv_se;
#pragma unroll
    for (int s2 = 1; s2 < 8; ++s2) av = (l == s2) ? e[s2] * inv_se : av;
    if (l < 8) {
      attnbuf[(size_t)row * 8 + l] = av;
      at4[w][l] = av;
    }
    __syncthreads();
#pragma unroll
    for (int c = 0; c < 3; ++c) {
      int d = t + 256 * c;
#pragma unroll
      for (int s2 = 0; s2 < 8; ++s2) {
        float acc = pooled[s2][d];
#pragma unroll
        for (int p = 0; p < 4; ++p) acc += at4[p][s2] * xs[p][d];
        pooled[s2][d] = acc;
      }
    }
    if (t < 8) asums[t] += at4[0][t] + at4[1][t] + at4[2][t] + at4[3][t];
    __syncthreads();
  }
  for (int i = t; i < 6144; i += 256)
    partials[((size_t)(chunk * 256 + b * 8)) * 768 + i] = ((float*)pooled)[i];
  if (t < 8) asump[chunk * 256 + b * 8 + t] = asums[t];
}

// ---------------- finish: reduce partials, updates=pooled@Wv, LN, MLP, residual ----------------
__global__ void finish_k(float* __restrict__ slots, const float* __restrict__ partials,
                         const float* __restrict__ asump, const float* __restrict__ Wv,
                         const float* __restrict__ bv, const float* __restrict__ g_ff,
                         const float* __restrict__ b_ff, const float* __restrict__ W1,
                         const float* __restrict__ b1, const float* __restrict__ W2,
                         const float* __restrict__ b2, float* __restrict__ invbuf) {
  __shared__ float bufA[4][768];
  __shared__ float bufB[4][768];
  __shared__ float asum[4], invs[4], rhos[4];
  int r0 = blockIdx.x * 4, t = threadIdx.x, w = t >> 6, l = t & 63;
  int row = r0 + w;
#pragma unroll
  for (int j = 0; j < 12; ++j) {
    int d = l + 64 * j;
    float a = 0.f;
    for (int c = 0; c < 16; ++c) a += partials[((size_t)(c * 256 + row)) * 768 + d];
    bufA[w][d] = a;
  }
  if (l == 0) {
    float a = 0.f;
    for (int c = 0; c < 16; ++c) a += asump[c * 256 + row];
    asum[w] = a;
  }
  __syncthreads();
  if (t < 4) {
    float a = asum[t];
    float iv = 1.f / (a + AEPS);
    invs[t] = iv;
    rhos[t] = a * iv;
  }
  __syncthreads();
  {  // updates = inv*(pooled@Wv) + rho*bv  -> bufB
    float acc[4][3] = {};
    for (int i = 0; i < 768; ++i) {
      float w0 = Wv[(size_t)i * 768 + t];
      float w1 = Wv[(size_t)i * 768 + t + 256];
      float w2 = Wv[(size_t)i * 768 + t + 512];
#pragma unroll
      for (int r = 0; r < 4; ++r) {
        float a = bufA[r][i];
        acc[r][0] += a * w0; acc[r][1] += a * w1; acc[r][2] += a * w2;
      }
    }
#pragma unroll
    for (int c = 0; c < 3; ++c) {
      int d = t + 256 * c;
      float bvv = bv[d];
#pragma unroll
      for (int r = 0; r < 4; ++r) bufB[r][d] = acc[r][c] * invs[r] + bvv * rhos[r];
    }
  }
  __syncthreads();
  {  // h = LN(updates)*g_ff + b_ff -> bufA
    float v[12], s = 0.f, ss = 0.f;
#pragma unroll
    for (int j = 0; j < 12; ++j) { v[j] = bufB[w][l + 64 * j]; s += v[j]; ss += v[j] * v[j]; }
#pragma unroll
    for (int o = 32; o; o >>= 1) { s += __shfl_xor(s, o); ss += __shfl_xor(ss, o); }
    float m = s * (1.f / 768.f), rsd = rsqrtf(ss * (1.f / 768.f) - m * m + LNEPS);
#pragma unroll
    for (int j = 0; j < 12; ++j) {
      int d = l + 64 * j;
      bufA[w][d] = (v[j] - m) * rsd * g_ff[d] + b_ff[d];
    }
  }
  __syncthreads();
  {  // t1 = relu(h@W1 + b1) -> bufB
    float acc[4][3];
#pragma unroll
    for (int r = 0; r < 4; ++r)
#pragma unroll
      for (int c = 0; c < 3; ++c) acc[r][c] = b1[t + 256 * c];
    for (int i = 0; i < 768; ++i) {
      float w0 = W1[(size_t)i * 768 + t];
      float w1 = W1[(size_t)i * 768 + t + 256];
      float w2 = W1[(size_t)i * 768 + t + 512];
#pragma unroll
      for (int r = 0; r < 4; ++r) {
        float a = bufA[r][i];
        acc[r][0] += a * w0; acc[r][1] += a * w1; acc[r][2] += a * w2;
      }
    }
    __syncthreads();
#pragma unroll
    for (int r = 0; r < 4; ++r)
#pragma unroll
      for (int c = 0; c < 3; ++c) bufB[r][t + 256 * c] = fmaxf(acc[r][c], 0.f);
  }
  __syncthreads();
  {  // slots += t1@W2 + b2
    float acc[4][3];
#pragma unroll
    for (int r = 0; r < 4; ++r)
#pragma unroll
      for (int c = 0; c < 3; ++c) acc[r][c] = b2[t + 256 * c];
    for (int i = 0; i < 768; ++i) {
      float w0 = W2[(size_t)i * 768 + t];
      float w1 = W2[(size_t)i * 768 + t + 256];
      float w2 = W2[(size_t)i * 768 + t + 512];
#pragma unroll
      for (int r = 0; r < 4; ++r) {
        float a = bufB[r][i];
        acc[r][0] += a * w0; acc[r][1] += a * w1; acc[r][2] += a * w2;
      }
    }
#pragma unroll
    for (int r = 0; r < 4; ++r)
#pragma unroll
      for (int c = 0; c < 3; ++c)
        slots[(size_t)(r0 + r) * 768 + t + 256 * c] += acc[r][c];
  }
  if (t < 4) invbuf[r0 + t] = invs[t];
}

// ---------------- output writers (fp32) ----------------
__global__ void out_slots_k(const float* __restrict__ slots, float* __restrict__ out) {
  int i = blockIdx.x * 256 + threadIdx.x;  // 196608
  out[i] = slots[i];
}
__global__ void out_attn_k(const float* __restrict__ attnbuf, const float* __restrict__ invbuf,
                           float* __restrict__ out) {
  int i = blockIdx.x * 256 + threadIdx.x;  // 262144 ; layout [b][n][s]
  out[196608 + i] = attnbuf[i] * invbuf[((i >> 13) << 3) + (i & 7)];
}

extern "C" void kernel_launch(void* const* d_in, const int* in_sizes, int n_in,
                              void* d_out, int out_size, void* d_ws, size_t ws_size,
                              hipStream_t stream) {
  (void)in_sizes; (void)n_in; (void)out_size; (void)ws_size;
  const float* slots0 = (const float*)d_in[0];
  const float* inputs = (const float*)d_in[1];
  const float* Wq = (const float*)d_in[2];
  const float* bq = (const float*)d_in[3];
  const float* Wk = (const float*)d_in[4];
  const float* bk = (const float*)d_in[5];
  const float* Wv = (const float*)d_in[6];
  const float* bv = (const float*)d_in[7];
  const float* g_in = (const float*)d_in[8];
  const float* b_in = (const float*)d_in[9];
  const float* g_s = (const float*)d_in[10];
  const float* b_s = (const float*)d_in[11];
  const float* g_ff = (const float*)d_in[12];
  const float* b_ff = (const float*)d_in[13];
  const float* W1 = (const float*)d_in[14];
  const float* b1 = (const float*)d_in[15];
  const float* W2 = (const float*)d_in[16];
  const float* b2 = (const float*)d_in[17];

  char* p = (char*)d_ws;
  float* WkT = (float*)p;     p += (size_t)768 * 768 * 4;
  float* mean = (float*)p;    p += 32768 * 4;
  float* rstd = (float*)p;    p += 32768 * 4;
  float* slotsf = (float*)p;  p += 256 * 768 * 4;
  float* qkbuf = (float*)p;   p += 256 * 768 * 4;
  float* qbkbuf = (float*)p;  p += 256 * 4;
  float* attnbuf = (float*)p; p += (size_t)32768 * 8 * 4;
  float* partials = (float*)p; p += (size_t)16 * 256 * 768 * 4;
  float* asump = (float*)p;   p += 16 * 256 * 4;
  float* invbuf = (float*)p;  p += 256 * 4;

  ln_stats_k<<<32768, 256, 0, stream>>>(inputs, mean, rstd);
  packT_k<<<dim3(24, 24), 256, 0, stream>>>(Wk, WkT);
  init_slots_k<<<768, 256, 0, stream>>>(slots0, slotsf);
  for (int it = 0; it < 3; ++it) {
    q_prep_k<<<64, 256, 0, stream>>>(slotsf, g_s, b_s, Wq, bq, WkT, bk, qkbuf, qbkbuf);
    attn_pool_k<<<dim3(16, 32), 256, 0, stream>>>(inputs, mean, rstd, g_in, b_in, qkbuf,
                                                  qbkbuf, attnbuf, partials, asump);
    finish_k<<<64, 256, 0, stream>>>(slotsf, partials, asump, Wv, bv, g_ff, b_ff, W1, b1,
                                     W2, b2, invbuf);
  }
  out_slots_k<<<768, 256, 0, stream>>>(slotsf, (float*)d_out);
  out_attn_k<<<1024, 256, 0, stream>>>(attnbuf, invbuf, (float*)d_out);
}

// Round 5
// 1046.426 us; speedup vs baseline: 1.3910x; 1.3910x over previous
//
#include <hip/hip_runtime.h>

#define LNEPS 1e-5f
#define AEPS 1e-8f
#define SCALE_Q 0.036084391824351615f  // 768^-0.5

// ---------------- LN stats over input rows (mean, rstd) ----------------
__global__ void ln_stats_k(const float* __restrict__ in, float* __restrict__ mean,
                           float* __restrict__ rstd) {
  int row = blockIdx.x, t = threadIdx.x;
  const float* p = in + (size_t)row * 768;
  float v0 = p[t], v1 = p[t + 256], v2 = p[t + 512];
  float s = v0 + v1 + v2, ss = v0 * v0 + v1 * v1 + v2 * v2;
#pragma unroll
  for (int o = 32; o; o >>= 1) { s += __shfl_down(s, o); ss += __shfl_down(ss, o); }
  __shared__ float sa[4], sb[4];
  if ((t & 63) == 0) { sa[t >> 6] = s; sb[t >> 6] = ss; }
  __syncthreads();
  if (t == 0) {
    float S = sa[0] + sa[1] + sa[2] + sa[3], SS = sb[0] + sb[1] + sb[2] + sb[3];
    float m = S * (1.f / 768.f);
    float var = SS * (1.f / 768.f) - m * m;
    mean[row] = m;
    rstd[row] = rsqrtf(var + LNEPS);
  }
}

// ---------------- transpose 768x768 fp32: WT[c][i] = W[i][c] ----------------
__global__ void packT_k(const float* __restrict__ W, float* __restrict__ WT) {
  __shared__ float tile[32][33];
  int c0 = blockIdx.x * 32, i0 = blockIdx.y * 32;
  int tx = threadIdx.x & 31, ty = threadIdx.x >> 5;  // 32x8
#pragma unroll
  for (int k = 0; k < 4; ++k)
    tile[ty + 8 * k][tx] = W[(size_t)(i0 + ty + 8 * k) * 768 + c0 + tx];
  __syncthreads();
#pragma unroll
  for (int k = 0; k < 4; ++k)
    WT[(size_t)(c0 + ty + 8 * k) * 768 + i0 + tx] = tile[tx][ty + 8 * k];
}

// ---------------- broadcast slots to all batch rows ----------------
__global__ void init_slots_k(const float* __restrict__ s0, float* __restrict__ slots) {
  int idx = blockIdx.x * 256 + threadIdx.x;  // 196608
  slots[idx] = s0[idx % 6144];
}

// ---------------- generic batched GEMV: out[256,768] = f(X[256,768] @ W[768,768]) -------
// grid (12 colblk, 16 rowblk), 256 thr. Thread (cx=t&15, rw=t>>4) owns row rw, cols c0+cx*4..+3.
// LN: apply layernorm (gamma,beta_ln) to X rows during staging.
// MODE 0: out = acc + bias[c]
// MODE 1: out = acc
// MODE 2: out = alpha[r]*acc + beta[r]*bias[c]
// MODE 3: out = relu(acc + bias[c])
// MODE 4: out += acc + bias[c]
template <bool LN, int MODE>
__global__ void gemv_k(const float* __restrict__ X, const float* __restrict__ W,
                       const float* __restrict__ bias, const float* __restrict__ gamma,
                       const float* __restrict__ beta_ln, const float* __restrict__ alpha,
                       const float* __restrict__ beta, float* __restrict__ out) {
  __shared__ float Xs[16][772];  // pad 772: rows land in distinct banks
  __shared__ float sm[16], sr[16];
  int c0 = blockIdx.x * 64, r0 = blockIdx.y * 16, t = threadIdx.x;
  // stage X tile (16 rows x 768), float4
  if (t < 192) {
#pragma unroll
    for (int r = 0; r < 16; ++r) {
      float4 v = *(const float4*)(X + (size_t)(r0 + r) * 768 + t * 4);
      *(float4*)&Xs[r][t * 4] = v;
    }
  }
  __syncthreads();
  if (LN) {
    int w = t >> 6, l = t & 63;
#pragma unroll
    for (int j = 0; j < 4; ++j) {
      int r = w * 4 + j;
      float s = 0.f, ss = 0.f;
#pragma unroll
      for (int m2 = 0; m2 < 12; ++m2) { float x = Xs[r][l + 64 * m2]; s += x; ss += x * x; }
#pragma unroll
      for (int o = 32; o; o >>= 1) { s += __shfl_xor(s, o); ss += __shfl_xor(ss, o); }
      if (l == 0) {
        float mu = s * (1.f / 768.f);
        sm[r] = mu;
        sr[r] = rsqrtf(ss * (1.f / 768.f) - mu * mu + LNEPS);
      }
    }
    __syncthreads();
    float g0 = gamma[t], g1 = gamma[t + 256], g2 = gamma[t + 512];
    float bb0 = beta_ln[t], bb1 = beta_ln[t + 256], bb2 = beta_ln[t + 512];
#pragma unroll
    for (int r = 0; r < 16; ++r) {
      float mu = sm[r], rs2 = sr[r];
      Xs[r][t] = (Xs[r][t] - mu) * rs2 * g0 + bb0;
      Xs[r][t + 256] = (Xs[r][t + 256] - mu) * rs2 * g1 + bb1;
      Xs[r][t + 512] = (Xs[r][t + 512] - mu) * rs2 * g2 + bb2;
    }
    __syncthreads();
  }
  int cx = t & 15, rw = t >> 4;
  int c = c0 + cx * 4;
  float ax = 0.f, ay = 0.f, az = 0.f, aw = 0.f;
  const float* wp = W + c;
  for (int k = 0; k < 768; k += 4) {
#pragma unroll
    for (int kk = 0; kk < 4; ++kk) {
      float4 wv = *(const float4*)(wp + (size_t)(k + kk) * 768);
      float xv = Xs[rw][k + kk];
      ax += xv * wv.x; ay += xv * wv.y; az += xv * wv.z; aw += xv * wv.w;
    }
  }
  int rr = r0 + rw;
  size_t oidx = (size_t)rr * 768 + c;
  float4 res;
  if (MODE == 0) {
    float4 b4 = *(const float4*)(bias + c);
    res.x = ax + b4.x; res.y = ay + b4.y; res.z = az + b4.z; res.w = aw + b4.w;
  } else if (MODE == 1) {
    res.x = ax; res.y = ay; res.z = az; res.w = aw;
  } else if (MODE == 2) {
    float4 b4 = *(const float4*)(bias + c);
    float al = alpha[rr], be = beta[rr];
    res.x = ax * al + b4.x * be; res.y = ay * al + b4.y * be;
    res.z = az * al + b4.z * be; res.w = aw * al + b4.w * be;
  } else if (MODE == 3) {
    float4 b4 = *(const float4*)(bias + c);
    res.x = fmaxf(ax + b4.x, 0.f); res.y = fmaxf(ay + b4.y, 0.f);
    res.z = fmaxf(az + b4.z, 0.f); res.w = fmaxf(aw + b4.w, 0.f);
  } else {
    float4 b4 = *(const float4*)(bias + c);
    float4 old = *(const float4*)(out + oidx);
    res.x = old.x + ax + b4.x; res.y = old.y + ay + b4.y;
    res.z = old.z + az + b4.z; res.w = old.w + aw + b4.w;
  }
  *(float4*)(out + oidx) = res;
}

// ---------------- qbk[row] = q[row] . bk ----------------
__global__ void qbk_k(const float* __restrict__ q, const float* __restrict__ bk,
                      float* __restrict__ qbk) {
  int row = blockIdx.x * 4 + (threadIdx.x >> 6), l = threadIdx.x & 63;
  float s = 0.f;
#pragma unroll
  for (int j = 0; j < 12; ++j) { int d = l + 64 * j; s += q[(size_t)row * 768 + d] * bk[d]; }
#pragma unroll
  for (int o = 32; o; o >>= 1) s += __shfl_xor(s, o);
  if (l == 0) qbk[row] = s;
}

// ---------------- fused dots+softmax+pool, one pass over inputs ----------------
__global__ void attn_pool_k(const float* __restrict__ in, const float* __restrict__ mean,
                            const float* __restrict__ rstd, const float* __restrict__ g_in,
                            const float* __restrict__ b_in, const float* __restrict__ qk,
                            const float* __restrict__ qbk, float* __restrict__ attnbuf,
                            float* __restrict__ partials, float* __restrict__ asump) {
  __shared__ float qks[8][768];
  __shared__ float pooled[8][768];
  __shared__ float xs[4][768];
  __shared__ float at4[4][8];
  __shared__ float asums[8];
  __shared__ float qbks[8];
  int chunk = blockIdx.x, b = blockIdx.y, t = threadIdx.x, w = t >> 6, l = t & 63;
  for (int i = t; i < 6144; i += 256) {
    ((float*)qks)[i] = qk[(size_t)b * 6144 + i];
    ((float*)pooled)[i] = 0.f;
  }
  if (t < 8) { asums[t] = 0.f; qbks[t] = qbk[b * 8 + t]; }
  __syncthreads();
  for (int rnd = 0; rnd < 16; ++rnd) {
    int n = chunk * 64 + rnd * 4 + w;
    int row = b * 1024 + n;
    const float* xp = in + (size_t)row * 768;
    float mu = mean[row], rs = rstd[row];
    float dots[8] = {};
#pragma unroll
    for (int j = 0; j < 12; ++j) {
      int d = l + 64 * j;
      float xv = (xp[d] - mu) * rs * g_in[d] + b_in[d];
      xs[w][d] = xv;
#pragma unroll
      for (int s2 = 0; s2 < 8; ++s2) dots[s2] += qks[s2][d] * xv;
    }
#pragma unroll
    for (int s2 = 0; s2 < 8; ++s2)
#pragma unroll
      for (int o = 32; o; o >>= 1) dots[s2] += __shfl_xor(dots[s2], o);
    float sc[8];
#pragma unroll
    for (int s2 = 0; s2 < 8; ++s2) sc[s2] = (dots[s2] + qbks[s2]) * SCALE_Q;
    float mx = sc[0];
#pragma unroll
    for (int s2 = 1; s2 < 8; ++s2) mx = fmaxf(mx, sc[s2]);
    float e[8], se = 0.f;
#pragma unroll
    for (int s2 = 0; s2 < 8; ++s2) { e[s2] = expf(sc[s2] - mx); se += e[s2]; }
    float inv_se = 1.f / se;
    float av = e[0] * inv_se;
#pragma unroll
    for (int s2 = 1; s2 < 8; ++s2) av = (l == s2) ? e[s2] * inv_se : av;
    if (l < 8) {
      attnbuf[(size_t)row * 8 + l] = av;
      at4[w][l] = av;
    }
    __syncthreads();
#pragma unroll
    for (int c = 0; c < 3; ++c) {
      int d = t + 256 * c;
#pragma unroll
      for (int s2 = 0; s2 < 8; ++s2) {
        float acc = pooled[s2][d];
#pragma unroll
        for (int p = 0; p < 4; ++p) acc += at4[p][s2] * xs[p][d];
        pooled[s2][d] = acc;
      }
    }
    if (t < 8) asums[t] += at4[0][t] + at4[1][t] + at4[2][t] + at4[3][t];
    __syncthreads();
  }
  for (int i = t; i < 6144; i += 256)
    partials[((size_t)(chunk * 256 + b * 8)) * 768 + i] = ((float*)pooled)[i];
  if (t < 8) asump[chunk * 256 + b * 8 + t] = asums[t];
}

// ---------------- reduce partials -> pooled[256,768]; asum -> inv, rho ----------------
__global__ void reduce_pool_k(const float* __restrict__ partials, const float* __restrict__ asump,
                              float* __restrict__ pooled, float* __restrict__ invbuf,
                              float* __restrict__ rhobuf) {
  int row = blockIdx.x, t = threadIdx.x;
#pragma unroll
  for (int c = 0; c < 3; ++c) {
    int d = t + 256 * c;
    float a = 0.f;
    for (int ch = 0; ch < 16; ++ch) a += partials[((size_t)(ch * 256 + row)) * 768 + d];
    pooled[(size_t)row * 768 + d] = a;
  }
  if (t == 0) {
    float a = 0.f;
    for (int ch = 0; ch < 16; ++ch) a += asump[ch * 256 + row];
    float iv = 1.f / (a + AEPS);
    invbuf[row] = iv;
    rhobuf[row] = a * iv;
  }
}

// ---------------- output writers (fp32) ----------------
__global__ void out_slots_k(const float* __restrict__ slots, float* __restrict__ out) {
  int i = blockIdx.x * 256 + threadIdx.x;  // 196608
  out[i] = slots[i];
}
__global__ void out_attn_k(const float* __restrict__ attnbuf, const float* __restrict__ invbuf,
                           float* __restrict__ out) {
  int i = blockIdx.x * 256 + threadIdx.x;  // 262144 ; layout [b][n][s]
  out[196608 + i] = attnbuf[i] * invbuf[((i >> 13) << 3) + (i & 7)];
}

extern "C" void kernel_launch(void* const* d_in, const int* in_sizes, int n_in,
                              void* d_out, int out_size, void* d_ws, size_t ws_size,
                              hipStream_t stream) {
  (void)in_sizes; (void)n_in; (void)out_size; (void)ws_size;
  const float* slots0 = (const float*)d_in[0];
  const float* inputs = (const float*)d_in[1];
  const float* Wq = (const float*)d_in[2];
  const float* bq = (const float*)d_in[3];
  const float* Wk = (const float*)d_in[4];
  const float* bk = (const float*)d_in[5];
  const float* Wv = (const float*)d_in[6];
  const float* bv = (const float*)d_in[7];
  const float* g_in = (const float*)d_in[8];
  const float* b_in = (const float*)d_in[9];
  const float* g_s = (const float*)d_in[10];
  const float* b_s = (const float*)d_in[11];
  const float* g_ff = (const float*)d_in[12];
  const float* b_ff = (const float*)d_in[13];
  const float* W1 = (const float*)d_in[14];
  const float* b1 = (const float*)d_in[15];
  const float* W2 = (const float*)d_in[16];
  const float* b2 = (const float*)d_in[17];

  char* p = (char*)d_ws;
  float* WkT = (float*)p;      p += (size_t)768 * 768 * 4;
  float* mean = (float*)p;     p += 32768 * 4;
  float* rstd = (float*)p;     p += 32768 * 4;
  float* slotsf = (float*)p;   p += 256 * 768 * 4;
  float* qbuf = (float*)p;     p += 256 * 768 * 4;
  float* qkbuf = (float*)p;    p += 256 * 768 * 4;
  float* qbkbuf = (float*)p;   p += 256 * 4;
  float* attnbuf = (float*)p;  p += (size_t)32768 * 8 * 4;
  float* partials = (float*)p; p += (size_t)16 * 256 * 768 * 4;
  float* asump = (float*)p;    p += 16 * 256 * 4;
  float* pooled = (float*)p;   p += 256 * 768 * 4;
  float* invbuf = (float*)p;   p += 256 * 4;
  float* rhobuf = (float*)p;   p += 256 * 4;
  float* updbuf = (float*)p;   p += 256 * 768 * 4;
  float* t1buf = (float*)p;    p += 256 * 768 * 4;

  dim3 ggrid(12, 16);
  ln_stats_k<<<32768, 256, 0, stream>>>(inputs, mean, rstd);
  packT_k<<<dim3(24, 24), 256, 0, stream>>>(Wk, WkT);
  init_slots_k<<<768, 256, 0, stream>>>(slots0, slotsf);
  for (int it = 0; it < 3; ++it) {
    gemv_k<true, 0><<<ggrid, 256, 0, stream>>>(slotsf, Wq, bq, g_s, b_s, nullptr, nullptr, qbuf);
    qbk_k<<<64, 256, 0, stream>>>(qbuf, bk, qbkbuf);
    gemv_k<false, 1><<<ggrid, 256, 0, stream>>>(qbuf, WkT, nullptr, nullptr, nullptr, nullptr,
                                                nullptr, qkbuf);
    attn_pool_k<<<dim3(16, 32), 256, 0, stream>>>(inputs, mean, rstd, g_in, b_in, qkbuf,
                                                  qbkbuf, attnbuf, partials, asump);
    reduce_pool_k<<<256, 256, 0, stream>>>(partials, asump, pooled, invbuf, rhobuf);
    gemv_k<false, 2><<<ggrid, 256, 0, stream>>>(pooled, Wv, bv, nullptr, nullptr, invbuf,
                                                rhobuf, updbuf);
    gemv_k<true, 3><<<ggrid, 256, 0, stream>>>(updbuf, W1, b1, g_ff, b_ff, nullptr, nullptr,
                                               t1buf);
    gemv_k<false, 4><<<ggrid, 256, 0, stream>>>(t1buf, W2, b2, nullptr, nullptr, nullptr,
                                                nullptr, slotsf);
  }
  out_slots_k<<<768, 256, 0, stream>>>(slotsf, (float*)d_out);
  out_attn_k<<<1024, 256, 0, stream>>>(attnbuf, invbuf, (float*)d_out);
}

// Round 6
// 747.176 us; speedup vs baseline: 1.9480x; 1.4005x over previous
//
#include <hip/hip_runtime.h>

#define LNEPS 1e-5f
#define AEPS 1e-8f
#define SCALE_Q 0.036084391824351615f  // 768^-0.5

// ---------------- transpose 768x768 fp32: WT[c][i] = W[i][c] ----------------
__global__ void packT_k(const float* __restrict__ W, float* __restrict__ WT) {
  __shared__ float tile[32][33];
  int c0 = blockIdx.x * 32, i0 = blockIdx.y * 32;
  int tx = threadIdx.x & 31, ty = threadIdx.x >> 5;  // 32x8
#pragma unroll
  for (int k = 0; k < 4; ++k)
    tile[ty + 8 * k][tx] = W[(size_t)(i0 + ty + 8 * k) * 768 + c0 + tx];
  __syncthreads();
#pragma unroll
  for (int k = 0; k < 4; ++k)
    WT[(size_t)(c0 + ty + 8 * k) * 768 + i0 + tx] = tile[tx][ty + 8 * k];
}

// ---------------- broadcast slots to all batch rows ----------------
__global__ void init_slots_k(const float* __restrict__ s0, float* __restrict__ slots) {
  int idx = blockIdx.x * 256 + threadIdx.x;  // 196608
  slots[idx] = s0[idx % 6144];
}

// ---------------- generic batched GEMV, split-k x4, 1024 threads ----------------
// out[256,768] = f(X[256,768] @ W[768,768]); grid (12 colblk, 16 rowblk).
// thread: cx=t&15 (4 cols), rw=(t>>4)&15 (row), kg=t>>8 (k-quarter).
// MODE 0: acc+bias | 1: acc | 2: alpha[r]*acc+beta[r]*bias | 3: relu(acc+bias) | 4: out+=acc+bias
template <bool LN, int MODE>
__global__ void gemv_k(const float* __restrict__ X, const float* __restrict__ W,
                       const float* __restrict__ bias, const float* __restrict__ gamma,
                       const float* __restrict__ beta_ln, const float* __restrict__ alpha,
                       const float* __restrict__ beta, float* __restrict__ out) {
  __shared__ float Xs[16][772];
  __shared__ float sm[16], sr[16];
  int c0 = blockIdx.x * 64, r0 = blockIdx.y * 16, t = threadIdx.x;
  // stage 16x768 with 1024 threads (3 float4 each)
#pragma unroll
  for (int j = 0; j < 3; ++j) {
    int fidx = j * 1024 + t;
    int r = fidx / 192, c4 = fidx % 192;
    *(float4*)&Xs[r][c4 * 4] = *(const float4*)(X + (size_t)(r0 + r) * 768 + c4 * 4);
  }
  __syncthreads();
  if (LN) {
    if (t < 256) {
      int w = t >> 6, l = t & 63;
#pragma unroll
      for (int j = 0; j < 4; ++j) {
        int r = w * 4 + j;
        float s = 0.f, ss = 0.f;
#pragma unroll
        for (int m2 = 0; m2 < 12; ++m2) { float x = Xs[r][l + 64 * m2]; s += x; ss += x * x; }
#pragma unroll
        for (int o = 32; o; o >>= 1) { s += __shfl_xor(s, o); ss += __shfl_xor(ss, o); }
        if (l == 0) {
          float mu = s * (1.f / 768.f);
          sm[r] = mu;
          sr[r] = rsqrtf(ss * (1.f / 768.f) - mu * mu + LNEPS);
        }
      }
    }
    __syncthreads();
#pragma unroll
    for (int j = 0; j < 12; ++j) {
      int idx = j * 1024 + t;
      int r = idx / 768, d = idx % 768;
      Xs[r][d] = (Xs[r][d] - sm[r]) * sr[r] * gamma[d] + beta_ln[d];
    }
    __syncthreads();
  }
  int cx = t & 15, rw = (t >> 4) & 15, kg = t >> 8;
  int c = c0 + cx * 4;
  float ax = 0.f, ay = 0.f, az = 0.f, aw = 0.f;
  const float* wp = W + c;
  int k0 = kg * 192;
  for (int k = k0; k < k0 + 192; k += 4) {
#pragma unroll
    for (int kk = 0; kk < 4; ++kk) {
      float4 wv = *(const float4*)(wp + (size_t)(k + kk) * 768);
      float xv = Xs[rw][k + kk];
      ax += xv * wv.x; ay += xv * wv.y; az += xv * wv.z; aw += xv * wv.w;
    }
  }
  __syncthreads();  // all kg done reading Xs; reuse as reduce buffer
  float* red = (float*)Xs;
  if (kg > 0) {
    float4 v; v.x = ax; v.y = ay; v.z = az; v.w = aw;
    *(float4*)&red[(size_t)(((kg - 1) * 256 + rw * 16 + cx)) * 4] = v;
  }
  __syncthreads();
  if (kg == 0) {
#pragma unroll
    for (int g = 1; g < 4; ++g) {
      float4 v = *(const float4*)&red[(size_t)(((g - 1) * 256 + rw * 16 + cx)) * 4];
      ax += v.x; ay += v.y; az += v.z; aw += v.w;
    }
    int rr = r0 + rw;
    size_t oidx = (size_t)rr * 768 + c;
    float4 res;
    if (MODE == 0) {
      float4 b4 = *(const float4*)(bias + c);
      res.x = ax + b4.x; res.y = ay + b4.y; res.z = az + b4.z; res.w = aw + b4.w;
    } else if (MODE == 1) {
      res.x = ax; res.y = ay; res.z = az; res.w = aw;
    } else if (MODE == 2) {
      float4 b4 = *(const float4*)(bias + c);
      float al = alpha[rr], be = beta[rr];
      res.x = ax * al + b4.x * be; res.y = ay * al + b4.y * be;
      res.z = az * al + b4.z * be; res.w = aw * al + b4.w * be;
    } else if (MODE == 3) {
      float4 b4 = *(const float4*)(bias + c);
      res.x = fmaxf(ax + b4.x, 0.f); res.y = fmaxf(ay + b4.y, 0.f);
      res.z = fmaxf(az + b4.z, 0.f); res.w = fmaxf(aw + b4.w, 0.f);
    } else {
      float4 b4 = *(const float4*)(bias + c);
      float4 old = *(const float4*)(out + oidx);
      res.x = old.x + ax + b4.x; res.y = old.y + ay + b4.y;
      res.z = old.z + az + b4.z; res.w = old.w + aw + b4.w;
    }
    *(float4*)(out + oidx) = res;
  }
}

// ---------------- per-slot scalars: Sq = qk.g_in ; c0 = qk.b_in + q.bk ----------------
__global__ void qprep_k(const float* __restrict__ q, const float* __restrict__ qk,
                        const float* __restrict__ g_in, const float* __restrict__ b_in,
                        const float* __restrict__ bk, float* __restrict__ Sqbuf,
                        float* __restrict__ c0buf) {
  int row = blockIdx.x * 4 + (threadIdx.x >> 6), l = threadIdx.x & 63;
  float aS = 0.f, aC = 0.f;
#pragma unroll
  for (int j = 0; j < 12; ++j) {
    int d = l + 64 * j;
    float qkv = qk[(size_t)row * 768 + d];
    aS += qkv * g_in[d];
    aC += qkv * b_in[d] + q[(size_t)row * 768 + d] * bk[d];
  }
#pragma unroll
  for (int o = 32; o; o >>= 1) { aS += __shfl_xor(aS, o); aC += __shfl_xor(aC, o); }
  if (l == 0) { Sqbuf[row] = aS; c0buf[row] = aC; }
}

// ---------------- dots+softmax over raw x; writes attn, w=a*r; atomics A0,A1 ----------------
// grid (32 chunk, 32 b), 256 thr = 4 waves x 8 rows
__global__ void dots_k(const float* __restrict__ in, const float* __restrict__ qk,
                       const float* __restrict__ g_in, const float* __restrict__ Sqbuf,
                       const float* __restrict__ c0buf, float* __restrict__ attnbuf,
                       float* __restrict__ wbuf, float* __restrict__ gA0,
                       float* __restrict__ gA1) {
  __shared__ float qkgs[8][768];
  __shared__ float c0s[8], Sqs[8];
  __shared__ float redA[4][8], redB[4][8];
  int chunk = blockIdx.x, b = blockIdx.y, t = threadIdx.x, w = t >> 6, l = t & 63;
#pragma unroll
  for (int s2 = 0; s2 < 8; ++s2)
    for (int d = t; d < 768; d += 256)
      qkgs[s2][d] = qk[(size_t)b * 6144 + s2 * 768 + d] * g_in[d];
  if (t < 8) { c0s[t] = c0buf[b * 8 + t]; Sqs[t] = Sqbuf[b * 8 + t]; }
  __syncthreads();
  float aA0[8] = {}, aA1[8] = {};
  for (int rr = 0; rr < 8; ++rr) {
    int n = chunk * 32 + w * 8 + rr;
    size_t row = (size_t)b * 1024 + n;
    const float* xp = in + row * 768;
    float v[12], s = 0.f, ss = 0.f;
#pragma unroll
    for (int j = 0; j < 12; ++j) { v[j] = xp[l + 64 * j]; s += v[j]; ss += v[j] * v[j]; }
#pragma unroll
    for (int o = 32; o; o >>= 1) { s += __shfl_xor(s, o); ss += __shfl_xor(ss, o); }
    float mu = s * (1.f / 768.f), r = rsqrtf(ss * (1.f / 768.f) - mu * mu + LNEPS);
    float ds[8] = {};
#pragma unroll
    for (int j = 0; j < 12; ++j) {
      float xv = v[j];
      int d = l + 64 * j;
#pragma unroll
      for (int s2 = 0; s2 < 8; ++s2) ds[s2] += qkgs[s2][d] * xv;
    }
#pragma unroll
    for (int s2 = 0; s2 < 8; ++s2)
#pragma unroll
      for (int o = 32; o; o >>= 1) ds[s2] += __shfl_xor(ds[s2], o);
    float sc[8];
    float rmu = r * mu;
#pragma unroll
    for (int s2 = 0; s2 < 8; ++s2)
      sc[s2] = (r * ds[s2] - rmu * Sqs[s2] + c0s[s2]) * SCALE_Q;
    float mx = sc[0];
#pragma unroll
    for (int s2 = 1; s2 < 8; ++s2) mx = fmaxf(mx, sc[s2]);
    float e[8], se = 0.f;
#pragma unroll
    for (int s2 = 0; s2 < 8; ++s2) { e[s2] = expf(sc[s2] - mx); se += e[s2]; }
    float inv_se = 1.f / se;
    if (l == 0) {
#pragma unroll
      for (int s2 = 0; s2 < 8; ++s2) {
        float a = e[s2] * inv_se;
        attnbuf[row * 8 + s2] = a;
        wbuf[row * 8 + s2] = a * r;
      }
    }
#pragma unroll
    for (int s2 = 0; s2 < 8; ++s2) {
      float a = e[s2] * inv_se;
      aA0[s2] += a;
      aA1[s2] += a * rmu;
    }
  }
  if (l == 0) {
#pragma unroll
    for (int s2 = 0; s2 < 8; ++s2) { redA[w][s2] = aA0[s2]; redB[w][s2] = aA1[s2]; }
  }
  __syncthreads();
  if (t < 8) {
    float sA = redA[0][t] + redA[1][t] + redA[2][t] + redA[3][t];
    float sB = redB[0][t] + redB[1][t] + redB[2][t] + redB[3][t];
    atomicAdd(&gA0[b * 8 + t], sA);
    atomicAdd(&gA1[b * 8 + t], sB);
  }
}

// ---------------- pool raw x with weights w: partials[chunk][b*8+s][768] ----------------
// grid (16 chunk, 32 b), 256 thr
__global__ void pool_k(const float* __restrict__ in, const float* __restrict__ wbuf,
                       float* __restrict__ partials) {
  __shared__ float ws[64][8];
  int chunk = blockIdx.x, b = blockIdx.y, t = threadIdx.x;
  for (int i = t; i < 512; i += 256)
    ((float*)ws)[i] = wbuf[((size_t)b * 1024 + chunk * 64) * 8 + i];
  __syncthreads();
  float acc[8][3] = {};
  const float* xp = in + ((size_t)b * 1024 + chunk * 64) * 768;
  for (int nn = 0; nn < 64; ++nn) {
    float x0 = xp[(size_t)nn * 768 + t];
    float x1 = xp[(size_t)nn * 768 + t + 256];
    float x2 = xp[(size_t)nn * 768 + t + 512];
#pragma unroll
    for (int s2 = 0; s2 < 8; ++s2) {
      float wv = ws[nn][s2];
      acc[s2][0] += wv * x0; acc[s2][1] += wv * x1; acc[s2][2] += wv * x2;
    }
  }
#pragma unroll
  for (int s2 = 0; s2 < 8; ++s2) {
    size_t base = ((size_t)(chunk * 256 + b * 8 + s2)) * 768;
    partials[base + t] = acc[s2][0];
    partials[base + t + 256] = acc[s2][1];
    partials[base + t + 512] = acc[s2][2];
  }
}

// ---------------- reduce partials + LN-fixup -> pooled ; inv, rho ----------------
__global__ void reduce_fix_k(const float* __restrict__ partials, const float* __restrict__ gA0,
                             const float* __restrict__ gA1, const float* __restrict__ g_in,
                             const float* __restrict__ b_in, float* __restrict__ pooled,
                             float* __restrict__ invbuf, float* __restrict__ rhobuf) {
  int row = blockIdx.x, t = threadIdx.x;  // row = b*8+s
  float A0 = gA0[row], A1 = gA1[row];
#pragma unroll
  for (int c = 0; c < 3; ++c) {
    int d = t + 256 * c;
    float a = 0.f;
    for (int ch = 0; ch < 16; ++ch) a += partials[((size_t)(ch * 256 + row)) * 768 + d];
    pooled[(size_t)row * 768 + d] = g_in[d] * (a - A1) + b_in[d] * A0;
  }
  if (t == 0) {
    float iv = 1.f / (A0 + AEPS);
    invbuf[row] = iv;
    rhobuf[row] = A0 * iv;
  }
}

// ---------------- output writers (fp32) ----------------
__global__ void out_slots_k(const float* __restrict__ slots, float* __restrict__ out) {
  int i = blockIdx.x * 256 + threadIdx.x;  // 196608
  out[i] = slots[i];
}
__global__ void out_attn_k(const float* __restrict__ attnbuf, const float* __restrict__ invbuf,
                           float* __restrict__ out) {
  int i = blockIdx.x * 256 + threadIdx.x;  // 262144 ; layout [b][n][s]
  out[196608 + i] = attnbuf[i] * invbuf[((i >> 13) << 3) + (i & 7)];
}

extern "C" void kernel_launch(void* const* d_in, const int* in_sizes, int n_in,
                              void* d_out, int out_size, void* d_ws, size_t ws_size,
                              hipStream_t stream) {
  (void)in_sizes; (void)n_in; (void)out_size; (void)ws_size;
  const float* slots0 = (const float*)d_in[0];
  const float* inputs = (const float*)d_in[1];
  const float* Wq = (const float*)d_in[2];
  const float* bq = (const float*)d_in[3];
  const float* Wk = (const float*)d_in[4];
  const float* bk = (const float*)d_in[5];
  const float* Wv = (const float*)d_in[6];
  const float* bv = (const float*)d_in[7];
  const float* g_in = (const float*)d_in[8];
  const float* b_in = (const float*)d_in[9];
  const float* g_s = (const float*)d_in[10];
  const float* b_s = (const float*)d_in[11];
  const float* g_ff = (const float*)d_in[12];
  const float* b_ff = (const float*)d_in[13];
  const float* W1 = (const float*)d_in[14];
  const float* b1 = (const float*)d_in[15];
  const float* W2 = (const float*)d_in[16];
  const float* b2 = (const float*)d_in[17];

  char* p = (char*)d_ws;
  float* WkT = (float*)p;      p += (size_t)768 * 768 * 4;
  float* slotsf = (float*)p;   p += 256 * 768 * 4;
  float* qbuf = (float*)p;     p += 256 * 768 * 4;
  float* qkbuf = (float*)p;    p += 256 * 768 * 4;
  float* Sqbuf = (float*)p;    p += 256 * 4;
  float* c0buf = (float*)p;    p += 256 * 4;
  float* attnbuf = (float*)p;  p += (size_t)32768 * 8 * 4;
  float* wbuf = (float*)p;     p += (size_t)32768 * 8 * 4;
  float* partials = (float*)p; p += (size_t)16 * 256 * 768 * 4;
  float* gA0 = (float*)p;      p += 256 * 4;
  float* gA1 = (float*)p;      p += 256 * 4;
  float* pooled = (float*)p;   p += 256 * 768 * 4;
  float* invbuf = (float*)p;   p += 256 * 4;
  float* rhobuf = (float*)p;   p += 256 * 4;
  float* updbuf = (float*)p;   p += 256 * 768 * 4;
  float* t1buf = (float*)p;    p += 256 * 768 * 4;

  dim3 ggrid(12, 16);
  packT_k<<<dim3(24, 24), 256, 0, stream>>>(Wk, WkT);
  init_slots_k<<<768, 256, 0, stream>>>(slots0, slotsf);
  for (int it = 0; it < 3; ++it) {
    gemv_k<true, 0><<<ggrid, 1024, 0, stream>>>(slotsf, Wq, bq, g_s, b_s, nullptr, nullptr, qbuf);
    gemv_k<false, 1><<<ggrid, 1024, 0, stream>>>(qbuf, WkT, nullptr, nullptr, nullptr, nullptr,
                                                 nullptr, qkbuf);
    qprep_k<<<64, 256, 0, stream>>>(qbuf, qkbuf, g_in, b_in, bk, Sqbuf, c0buf);
    hipMemsetAsync(gA0, 0, 2 * 256 * 4, stream);  // gA0 and gA1 are adjacent
    dots_k<<<dim3(32, 32), 256, 0, stream>>>(inputs, qkbuf, g_in, Sqbuf, c0buf, attnbuf, wbuf,
                                             gA0, gA1);
    pool_k<<<dim3(16, 32), 256, 0, stream>>>(inputs, wbuf, partials);
    reduce_fix_k<<<256, 256, 0, stream>>>(partials, gA0, gA1, g_in, b_in, pooled, invbuf,
                                          rhobuf);
    gemv_k<false, 2><<<ggrid, 1024, 0, stream>>>(pooled, Wv, bv, nullptr, nullptr, invbuf,
                                                 rhobuf, updbuf);
    gemv_k<true, 3><<<ggrid, 1024, 0, stream>>>(updbuf, W1, b1, g_ff, b_ff, nullptr, nullptr,
                                                t1buf);
    gemv_k<false, 4><<<ggrid, 1024, 0, stream>>>(t1buf, W2, b2, nullptr, nullptr, nullptr,
                                                 nullptr, slotsf);
  }
  out_slots_k<<<768, 256, 0, stream>>>(slotsf, (float*)d_out);
  out_attn_k<<<1024, 256, 0, stream>>>(attnbuf, invbuf, (float*)d_out);
}